// Round 3
// baseline (113.516 us; speedup 1.0000x reference)
//
#include <hip/hip_runtime.h>
#include <math.h>

#define NB 16
#define NA 3
#define NC 80
#define GS 4096                 // 64*64 spatial
#define NPOS (NB * NA * GS)     // 196608
#define LDS_S 65                // padded stride for lds[ch][p]; odd -> conflict-free columns

__device__ __forceinline__ float sigmoidf_(float v) {
    return 1.0f / (1.0f + __expf(-v));
}

// One block = one (b,a) pair x 64 consecutive spatial positions (one grid row).
// Read phase:  80 cls channels x 64 pos, float4 coalesced loads, sigmoid -> LDS transpose.
// Write phase: 64x80 output tile is one contiguous 20KB region -> coalesced float4 stores.
__global__ __launch_bounds__(256) void yolo_kernel(const float* __restrict__ x,
                                                   const float* __restrict__ anchors,
                                                   float* __restrict__ out) {
    __shared__ float lds[NC * LDS_S];
    const int tid  = threadIdx.x;
    const int ba   = blockIdx.x >> 6;   // which (b,a), 0..47
    const int tile = blockIdx.x & 63;   // grid row i
    const int s0   = tile << 6;
    const float* __restrict__ xb = x + (size_t)ba * 85 * GS + s0;

    // ---- Phase B reads: float4 loads (wave = 4 channels x 256B segments), sigmoid, LDS[ch][p] ----
    #pragma unroll
    for (int k = 0; k < 5; ++k) {
        const int e4 = tid + k * 256;   // 0..1279 = 80 ch x 16 float4-groups
        const int ch = e4 >> 4;
        const int p  = (e4 & 15) << 2;
        const float4 v = *reinterpret_cast<const float4*>(xb + (size_t)(5 + ch) * GS + p);
        float* l = lds + ch * LDS_S + p;
        l[0] = sigmoidf_(v.x);
        l[1] = sigmoidf_(v.y);
        l[2] = sigmoidf_(v.z);
        l[3] = sigmoidf_(v.w);
    }

    // ---- Phase A: wave 0 does boxes + conf (already-coalesced writes) ----
    if (tid < 64) {
        const int p = tid;
        const int t = ba * GS + s0 + p;         // global position index
        const float tx = xb[0 * GS + p];
        const float ty = xb[1 * GS + p];
        const float tw = xb[2 * GS + p];
        const float th = xb[3 * GS + p];
        const float tc = xb[4 * GS + p];
        const int a = ba % NA;
        const float aw = anchors[a * 2 + 0];    // anchors[a][0]*g0/scale(g0) = anchors[a][0]
        const float ah = anchors[a * 2 + 1];
        float4 box;
        box.x = (sigmoidf_(tx) + (float)tile) * (1.0f / 64.0f);  // grid_x = row i
        box.y = (sigmoidf_(ty) + (float)p)    * (1.0f / 64.0f);  // grid_y = col j
        box.z = __expf(tw) * aw;
        box.w = __expf(th) * ah;
        reinterpret_cast<float4*>(out)[t] = box;
        out[NPOS * 4 + t] = sigmoidf_(tc);
    }

    __syncthreads();

    // ---- Phase B writes: contiguous 5120-float tile, coalesced float4 ----
    float4* __restrict__ out4 =
        reinterpret_cast<float4*>(out + (size_t)NPOS * 5 + (size_t)(ba * GS + s0) * NC);
    #pragma unroll
    for (int k = 0; k < 5; ++k) {
        const int o4 = tid + k * 256;   // 0..1279
        const int o  = o4 * 4;
        const int p  = o / 80;
        const int ch = o - p * 80;      // multiple of 4, <= 76
        float4 v;
        v.x = lds[(ch + 0) * LDS_S + p];
        v.y = lds[(ch + 1) * LDS_S + p];
        v.z = lds[(ch + 2) * LDS_S + p];
        v.w = lds[(ch + 3) * LDS_S + p];
        out4[o4] = v;
    }
}

extern "C" void kernel_launch(void* const* d_in, const int* in_sizes, int n_in,
                              void* d_out, int out_size, void* d_ws, size_t ws_size,
                              hipStream_t stream) {
    const float* x       = (const float*)d_in[0];
    const float* anchors = (const float*)d_in[1];
    float* out           = (float*)d_out;
    const int blocks = NB * NA * 64;    // 3072 blocks, one per (b,a,row)
    yolo_kernel<<<blocks, 256, 0, stream>>>(x, anchors, out);
}